// Round 6
// baseline (10.789 us; speedup 1.0000x reference)
//
#include <hip/hip_runtime.h>
#include <math.h>

#define PI_F    3.14159265358979323846f
#define PIO2_F  1.57079632679489661923f

typedef float f4 __attribute__((ext_vector_type(4)));

// Fast atan, max abs err ~1e-7 over full range.
__device__ __forceinline__ float fast_atan(float x) {
    float a = __builtin_fabsf(x);
    bool inv = a > 1.0f;
    float t = inv ? __fdividef(1.0f, a) : a;
    float t2 = t * t;
    float p = -0.0040540580f;
    p = fmaf(p, t2,  0.0218612288f);
    p = fmaf(p, t2, -0.0559098861f);
    p = fmaf(p, t2,  0.0964200441f);
    p = fmaf(p, t2, -0.1390853351f);
    p = fmaf(p, t2,  0.1994653599f);
    p = fmaf(p, t2, -0.3332985605f);
    p = fmaf(p, t2,  0.9999993329f);
    float r = t * p;
    if (inv) r = PIO2_F - r;
    return copysignf(r, x);
}

// Order-preserving unsigned key for non-NaN floats.
__device__ __forceinline__ unsigned int ord_key(float x) {
    unsigned int u = __float_as_uint(x);
    return (u & 0x80000000u) ? ~u : (u | 0x80000000u);
}

// One wave (64 lanes) per (b,p), 16 waves per 1024-thread block (1 block/CU,
// 4x fewer workgroups to dispatch than the 256-thread variant). Params
// hoisted above the stream; argmax via packed (value,~idx) u64 max butterfly
// (first-max tie-break exact); uniform scalar tail on all lanes; lane 0 stores.
__global__ __launch_bounds__(1024) void rcnn_sparse3d_loss_kernel(
    const float* __restrict__ batch_loc,   // (B,P,3)
    const float* __restrict__ batch_dim,   // (B,P,3)
    const float* __restrict__ batch_rot_y, // (B,P,1)
    const float* __restrict__ rois,        // (B,P,4)
    const float* __restrict__ cls,         // (B,P,F)
    const float* __restrict__ off2,        // (B,P,2,F)
    const float* __restrict__ off3,        // (B,P,2,F)
    const float* __restrict__ dep,         // (B,P,F)
    const float* __restrict__ pre_dim,     // (B,P,3)
    const float* __restrict__ pre_rot,     // (B,P,2)
    const float* __restrict__ calib,       // (B,3,4)
    const float* __restrict__ trans,       // (B,2,3)
    const float* __restrict__ distc,       // (B,5)
    float* __restrict__ out,               // (B,P,1)
    int N, int Pn, int wmask, int wshift)
{
    const int wave = threadIdx.x >> 6;      // 0..15
    const int lane = threadIdx.x & 63;
    const int bp   = blockIdx.x * 16 + wave;
    if (bp >= N) return;
    const int b = bp / Pn;

    // ---- hoisted idx-independent loads (latency hides under streaming) ----
    const float* r  = rois      + (size_t)bp * 4;
    const float r0 = r[0], r1 = r[1], r2 = r[2], r3 = r[3];
    const float* t  = trans     + (size_t)b * 6;
    const float ta = t[0], tb = t[1], tc = t[2], td = t[3], te = t[4], tf = t[5];
    const float* K  = calib     + (size_t)b * 12;
    const float fx = K[0], cx = K[2], Tx = K[3];
    const float fy = K[5], cy = K[6], Tz = K[11];
    const float* dc = distc     + (size_t)b * 5;
    const float k1 = dc[0], k2 = dc[1], p1 = dc[2], p2 = dc[3], k3 = dc[4];
    const float* pr = pre_rot   + (size_t)bp * 2;
    const float rs = pr[0], rc = pr[1];
    const float* pd = pre_dim   + (size_t)bp * 3;
    const float pdw = pd[1], pdl = pd[2];
    const float* gd = batch_dim + (size_t)bp * 3;
    const float gdw = gd[1], gdl = gd[2];
    const float* gl = batch_loc + (size_t)bp * 3;
    const float glx = gl[0], glz = gl[2];
    const float gry = batch_rot_y[bp];

    // ---- wave-parallel argmax over F=1024 (first-max tie-break) ----
    const f4* c4 = reinterpret_cast<const f4*>(cls + (size_t)bp * 1024);
    // packed key: [ord(value) : 32 | (0xFFFFFFFF - idx) : 32]
    // u64-max  <=>  greater value, or equal value and LOWER index.
    unsigned long long best = 0ull;
    #pragma unroll
    for (int j = 0; j < 4; ++j) {
        f4 v = c4[j * 64 + lane];                 // coalesced: 64 lanes x 16B
        unsigned int base = 4u * (j * 64 + lane);
        #pragma unroll
        for (int e = 0; e < 4; ++e) {
            unsigned long long key =
                ((unsigned long long)ord_key(v[e]) << 32) |
                (0xFFFFFFFFu - (base + e));
            best = (key > best) ? key : best;
        }
    }
    #pragma unroll
    for (int s = 1; s < 64; s <<= 1) {
        unsigned long long o = __shfl_xor(best, s);
        best = (o > best) ? o : best;
    }
    const int idx = (int)(0xFFFFFFFFu - (unsigned int)best);  // uniform

    // ---- gathers at argmax index (uniform address -> broadcast loads) ----
    const size_t o2b = (size_t)bp * 2048;
    const float g2x  = off2[o2b + idx];
    const float g2y  = off2[o2b + 1024 + idx];
    const float g3x  = off3[o2b + idx];
    const float g3y  = off3[o2b + 1024 + idx];
    const float gdep = dep[(size_t)bp * 1024 + idx];

    // ---- 2D center ----
    const float Wf = (float)(wmask + 1);
    const float invW = __frcp_rn(Wf);               // exact: W is pow2
    const float ix = (float)(idx & wmask);
    const float iy = (float)(idx >> wshift);
    const float px = (ix + g2x) * (r2 - r0 + 1.0f) * invW + r0;
    const float py = (iy + g2y) * (r3 - r1 + 1.0f) * invW + r1;

    // ---- inverse affine ----
    const float invdet = __frcp_rn(ta * te - tb * td);
    const float ax = ( te * px - tb * py + (tb * tf - tc * te)) * invdet;
    const float ay = (-td * px + ta * py + (tc * td - ta * tf)) * invdet;

    // ---- undistort ----
    const float x0 = (ax - cx) * __frcp_rn(fx);
    const float y0 = (ay - cy) * __frcp_rn(fy);
    float ux = x0, uy = y0;
    if (!(k1 == 0.0f && k2 == 0.0f && p1 == 0.0f && p2 == 0.0f && k3 == 0.0f)) {
        #pragma unroll
        for (int it = 0; it < 5; ++it) {
            const float rr2 = ux * ux + uy * uy;
            const float icd = __fdividef(1.0f, 1.0f + ((k3 * rr2 + k2) * rr2 + k1) * rr2);
            const float dx  = 2.0f * p1 * ux * uy + p2 * (rr2 + 2.0f * ux * ux);
            const float dy  = p1 * (rr2 + 2.0f * uy * uy) + 2.0f * p2 * ux * uy;
            ux = (x0 - dx) * icd;
            uy = (y0 - dy) * icd;
        }
    }
    const float undx = fx * ux + cx;

    // ---- depth -> 3D ----
    const float fscale = fx * 0.001f;               // FOCAL_DEFAULT = 1000
    const float sig    = __fdividef(1.0f, 1.0f + __expf(-gdep));
    const float depth  = (__fdividef(1.0f, sig + 1e-6f) - 1.0f) * fscale;
    const float z3     = depth - Tz;
    float x3 = (undx * depth - Tx - cx * z3) * __frcp_rn(fx);
    x3 += g3x * fscale;
    // y3 unused by BEV iou

    // ---- rotation ----
    float alpha = fast_atan(__fdividef(rs, rc + 1e-7f)) + (rc < 0.0f ? PIO2_F : -PIO2_F);
    const float theta = fast_atan(__fdividef(x3, z3 + 1e-7f));
    float ry = alpha + theta;
    if (ry < -PI_F) ry += 2.0f * PI_F;
    else if (ry > PI_F) ry -= 2.0f * PI_F;

    // ---- BEV min/max (axis-aligned envelope of rotated box) ----
    float pcc, pss, gcc, gss;
    __sincosf(ry,  &pss, &pcc);
    __sincosf(gry, &gss, &gcc);

    auto bev_minmax = [](float w, float l, float lx, float lz, float cc, float ss,
                         float& mnx, float& mxx, float& mnz, float& mxz) {
        const float hx = l * 0.5f, hz = w * 0.5f;
        const float ex = __builtin_fabsf(cc * hx) + __builtin_fabsf(ss * hz);
        const float ez = __builtin_fabsf(ss * hx) + __builtin_fabsf(cc * hz);
        mnx = lx - ex; mxx = lx + ex;
        mnz = lz - ez; mxz = lz + ez;
    };

    float pmnx, pmxx, pmnz, pmxz, gmnx, gmxx, gmnz, gmxz;
    bev_minmax(pdw, pdl, x3,  z3,  pcc, pss, pmnx, pmxx, pmnz, pmxz);
    bev_minmax(gdw, gdl, glx, glz, gcc, gss, gmnx, gmxx, gmnz, gmxz);

    const float s1 = (pmxx - pmnx) * (pmxz - pmnz);
    const float s2 = (gmxx - gmnx) * (gmxz - gmnz);
    const float ww = fmaxf(fminf(pmxx, gmxx) - fmaxf(pmnx, gmnx), 0.0f);
    const float hh = fmaxf(fminf(pmxz, gmxz) - fmaxf(pmnz, gmnz), 0.0f);
    const float ov = ww * hh;
    const float iou = __fdividef(ov, s1 + s2 - ov + 1e-6f);

    if (lane == 0) out[bp] = iou;
}

extern "C" void kernel_launch(void* const* d_in, const int* in_sizes, int n_in,
                              void* d_out, int out_size, void* d_ws, size_t ws_size,
                              hipStream_t stream) {
    const float* batch_loc   = (const float*)d_in[0];
    const float* batch_dim   = (const float*)d_in[1];
    const float* batch_rot_y = (const float*)d_in[2];
    const float* rois        = (const float*)d_in[3];
    const float* pre_cls     = (const float*)d_in[4];
    const float* pre_2d      = (const float*)d_in[5];
    const float* pre_3d      = (const float*)d_in[6];
    const float* pre_depth   = (const float*)d_in[7];
    const float* pre_dim     = (const float*)d_in[8];
    const float* pre_rot     = (const float*)d_in[9];
    const float* calib       = (const float*)d_in[10];
    const float* trans_mat   = (const float*)d_in[11];
    const float* dist_coeffs = (const float*)d_in[12];
    float* out = (float*)d_out;

    const int N  = in_sizes[2];            // B*P
    const int Bn = in_sizes[10] / 12;      // calib is (B,3,4)
    const int Pn = N / Bn;
    const int F  = in_sizes[4] / N;        // 1024
    int Wk = 1; while (Wk * Wk < F) Wk <<= 1;   // 32
    int wshift = 0; while ((1 << wshift) < Wk) ++wshift;

    const int rows_per_block = 16;         // 1024 threads, 16 waves/block
    const int grid = (N + rows_per_block - 1) / rows_per_block;
    rcnn_sparse3d_loss_kernel<<<grid, 1024, 0, stream>>>(
        batch_loc, batch_dim, batch_rot_y, rois, pre_cls, pre_2d, pre_3d,
        pre_depth, pre_dim, pre_rot, calib, trans_mat, dist_coeffs,
        out, N, Pn, Wk - 1, wshift);
}

// Round 7
// 9.425 us; speedup vs baseline: 1.1447x; 1.1447x over previous
//
#include <hip/hip_runtime.h>
#include <math.h>

#define PI_F    3.14159265358979323846f
#define PIO2_F  1.57079632679489661923f

typedef float f4 __attribute__((ext_vector_type(4)));

// Fast atan, max abs err ~1e-7 over full range.
__device__ __forceinline__ float fast_atan(float x) {
    float a = __builtin_fabsf(x);
    bool inv = a > 1.0f;
    float t = inv ? __fdividef(1.0f, a) : a;
    float t2 = t * t;
    float p = -0.0040540580f;
    p = fmaf(p, t2,  0.0218612288f);
    p = fmaf(p, t2, -0.0559098861f);
    p = fmaf(p, t2,  0.0964200441f);
    p = fmaf(p, t2, -0.1390853351f);
    p = fmaf(p, t2,  0.1994653599f);
    p = fmaf(p, t2, -0.3332985605f);
    p = fmaf(p, t2,  0.9999993329f);
    float r = t * p;
    if (inv) r = PIO2_F - r;
    return copysignf(r, x);
}

// Order-preserving unsigned key for non-NaN floats.
__device__ __forceinline__ unsigned int ord_key(float x) {
    unsigned int u = __float_as_uint(x);
    return (u & 0x80000000u) ? ~u : (u | 0x80000000u);
}

// One wave (64 lanes) per (b,p). Params hoisted above the stream so their
// latency hides under it. Argmax via packed (value,~idx) u64 max butterfly
// (first-max tie-break exact). All 64 lanes run the uniform scalar tail
// redundantly; lane 0 stores.  [Best measured config: 9.52 us]
__global__ __launch_bounds__(256) void rcnn_sparse3d_loss_kernel(
    const float* __restrict__ batch_loc,   // (B,P,3)
    const float* __restrict__ batch_dim,   // (B,P,3)
    const float* __restrict__ batch_rot_y, // (B,P,1)
    const float* __restrict__ rois,        // (B,P,4)
    const float* __restrict__ cls,         // (B,P,F)
    const float* __restrict__ off2,        // (B,P,2,F)
    const float* __restrict__ off3,        // (B,P,2,F)
    const float* __restrict__ dep,         // (B,P,F)
    const float* __restrict__ pre_dim,     // (B,P,3)
    const float* __restrict__ pre_rot,     // (B,P,2)
    const float* __restrict__ calib,       // (B,3,4)
    const float* __restrict__ trans,       // (B,2,3)
    const float* __restrict__ distc,       // (B,5)
    float* __restrict__ out,               // (B,P,1)
    int N, int Pn, int wmask, int wshift)
{
    const int wave = threadIdx.x >> 6;
    const int lane = threadIdx.x & 63;
    const int bp   = blockIdx.x * 4 + wave;
    if (bp >= N) return;
    const int b = bp / Pn;

    // ---- hoisted idx-independent loads (latency hides under streaming) ----
    const float* r  = rois      + (size_t)bp * 4;
    const float r0 = r[0], r1 = r[1], r2 = r[2], r3 = r[3];
    const float* t  = trans     + (size_t)b * 6;
    const float ta = t[0], tb = t[1], tc = t[2], td = t[3], te = t[4], tf = t[5];
    const float* K  = calib     + (size_t)b * 12;
    const float fx = K[0], cx = K[2], Tx = K[3];
    const float fy = K[5], cy = K[6], Tz = K[11];
    const float* dc = distc     + (size_t)b * 5;
    const float k1 = dc[0], k2 = dc[1], p1 = dc[2], p2 = dc[3], k3 = dc[4];
    const float* pr = pre_rot   + (size_t)bp * 2;
    const float rs = pr[0], rc = pr[1];
    const float* pd = pre_dim   + (size_t)bp * 3;
    const float pdw = pd[1], pdl = pd[2];
    const float* gd = batch_dim + (size_t)bp * 3;
    const float gdw = gd[1], gdl = gd[2];
    const float* gl = batch_loc + (size_t)bp * 3;
    const float glx = gl[0], glz = gl[2];
    const float gry = batch_rot_y[bp];

    // ---- wave-parallel argmax over F=1024 (first-max tie-break) ----
    const f4* c4 = reinterpret_cast<const f4*>(cls + (size_t)bp * 1024);
    // packed key: [ord(value) : 32 | (0xFFFFFFFF - idx) : 32]
    // u64-max  <=>  greater value, or equal value and LOWER index.
    unsigned long long best = 0ull;
    #pragma unroll
    for (int j = 0; j < 4; ++j) {
        f4 v = c4[j * 64 + lane];                 // coalesced: 64 lanes x 16B
        unsigned int base = 4u * (j * 64 + lane);
        #pragma unroll
        for (int e = 0; e < 4; ++e) {
            unsigned long long key =
                ((unsigned long long)ord_key(v[e]) << 32) |
                (0xFFFFFFFFu - (base + e));
            best = (key > best) ? key : best;
        }
    }
    #pragma unroll
    for (int s = 1; s < 64; s <<= 1) {
        unsigned long long o = __shfl_xor(best, s);
        best = (o > best) ? o : best;
    }
    const int idx = (int)(0xFFFFFFFFu - (unsigned int)best);  // uniform

    // ---- gathers at argmax index (uniform address -> broadcast loads) ----
    const size_t o2b = (size_t)bp * 2048;
    const float g2x  = off2[o2b + idx];
    const float g2y  = off2[o2b + 1024 + idx];
    const float g3x  = off3[o2b + idx];
    const float g3y  = off3[o2b + 1024 + idx];
    const float gdep = dep[(size_t)bp * 1024 + idx];

    // ---- 2D center ----
    const float Wf = (float)(wmask + 1);
    const float invW = __frcp_rn(Wf);               // exact: W is pow2
    const float ix = (float)(idx & wmask);
    const float iy = (float)(idx >> wshift);
    const float px = (ix + g2x) * (r2 - r0 + 1.0f) * invW + r0;
    const float py = (iy + g2y) * (r3 - r1 + 1.0f) * invW + r1;

    // ---- inverse affine ----
    const float invdet = __frcp_rn(ta * te - tb * td);
    const float ax = ( te * px - tb * py + (tb * tf - tc * te)) * invdet;
    const float ay = (-td * px + ta * py + (tc * td - ta * tf)) * invdet;

    // ---- undistort ----
    const float x0 = (ax - cx) * __frcp_rn(fx);
    const float y0 = (ay - cy) * __frcp_rn(fy);
    float ux = x0, uy = y0;
    if (!(k1 == 0.0f && k2 == 0.0f && p1 == 0.0f && p2 == 0.0f && k3 == 0.0f)) {
        #pragma unroll
        for (int it = 0; it < 5; ++it) {
            const float rr2 = ux * ux + uy * uy;
            const float icd = __fdividef(1.0f, 1.0f + ((k3 * rr2 + k2) * rr2 + k1) * rr2);
            const float dx  = 2.0f * p1 * ux * uy + p2 * (rr2 + 2.0f * ux * ux);
            const float dy  = p1 * (rr2 + 2.0f * uy * uy) + 2.0f * p2 * ux * uy;
            ux = (x0 - dx) * icd;
            uy = (y0 - dy) * icd;
        }
    }
    const float undx = fx * ux + cx;

    // ---- depth -> 3D ----
    const float fscale = fx * 0.001f;               // FOCAL_DEFAULT = 1000
    const float sig    = __fdividef(1.0f, 1.0f + __expf(-gdep));
    const float depth  = (__fdividef(1.0f, sig + 1e-6f) - 1.0f) * fscale;
    const float z3     = depth - Tz;
    float x3 = (undx * depth - Tx - cx * z3) * __frcp_rn(fx);
    x3 += g3x * fscale;
    // y3 unused by BEV iou

    // ---- rotation ----
    float alpha = fast_atan(__fdividef(rs, rc + 1e-7f)) + (rc < 0.0f ? PIO2_F : -PIO2_F);
    const float theta = fast_atan(__fdividef(x3, z3 + 1e-7f));
    float ry = alpha + theta;
    if (ry < -PI_F) ry += 2.0f * PI_F;
    else if (ry > PI_F) ry -= 2.0f * PI_F;

    // ---- BEV min/max (axis-aligned envelope of rotated box) ----
    float pcc, pss, gcc, gss;
    __sincosf(ry,  &pss, &pcc);
    __sincosf(gry, &gss, &gcc);

    auto bev_minmax = [](float w, float l, float lx, float lz, float cc, float ss,
                         float& mnx, float& mxx, float& mnz, float& mxz) {
        const float hx = l * 0.5f, hz = w * 0.5f;
        const float ex = __builtin_fabsf(cc * hx) + __builtin_fabsf(ss * hz);
        const float ez = __builtin_fabsf(ss * hx) + __builtin_fabsf(cc * hz);
        mnx = lx - ex; mxx = lx + ex;
        mnz = lz - ez; mxz = lz + ez;
    };

    float pmnx, pmxx, pmnz, pmxz, gmnx, gmxx, gmnz, gmxz;
    bev_minmax(pdw, pdl, x3,  z3,  pcc, pss, pmnx, pmxx, pmnz, pmxz);
    bev_minmax(gdw, gdl, glx, glz, gcc, gss, gmnx, gmxx, gmnz, gmxz);

    const float s1 = (pmxx - pmnx) * (pmxz - pmnz);
    const float s2 = (gmxx - gmnx) * (gmxz - gmnz);
    const float ww = fmaxf(fminf(pmxx, gmxx) - fmaxf(pmnx, gmnx), 0.0f);
    const float hh = fmaxf(fminf(pmxz, gmxz) - fmaxf(pmnz, gmnz), 0.0f);
    const float ov = ww * hh;
    const float iou = __fdividef(ov, s1 + s2 - ov + 1e-6f);

    if (lane == 0) out[bp] = iou;
}

extern "C" void kernel_launch(void* const* d_in, const int* in_sizes, int n_in,
                              void* d_out, int out_size, void* d_ws, size_t ws_size,
                              hipStream_t stream) {
    const float* batch_loc   = (const float*)d_in[0];
    const float* batch_dim   = (const float*)d_in[1];
    const float* batch_rot_y = (const float*)d_in[2];
    const float* rois        = (const float*)d_in[3];
    const float* pre_cls     = (const float*)d_in[4];
    const float* pre_2d      = (const float*)d_in[5];
    const float* pre_3d      = (const float*)d_in[6];
    const float* pre_depth   = (const float*)d_in[7];
    const float* pre_dim     = (const float*)d_in[8];
    const float* pre_rot     = (const float*)d_in[9];
    const float* calib       = (const float*)d_in[10];
    const float* trans_mat   = (const float*)d_in[11];
    const float* dist_coeffs = (const float*)d_in[12];
    float* out = (float*)d_out;

    const int N  = in_sizes[2];            // B*P
    const int Bn = in_sizes[10] / 12;      // calib is (B,3,4)
    const int Pn = N / Bn;
    const int F  = in_sizes[4] / N;        // 1024
    int Wk = 1; while (Wk * Wk < F) Wk <<= 1;   // 32
    int wshift = 0; while ((1 << wshift) < Wk) ++wshift;

    const int waves_per_block = 4;         // 256 threads, 1 wave per row
    const int grid = (N + waves_per_block - 1) / waves_per_block;
    rcnn_sparse3d_loss_kernel<<<grid, 256, 0, stream>>>(
        batch_loc, batch_dim, batch_rot_y, rois, pre_cls, pre_2d, pre_3d,
        pre_depth, pre_dim, pre_rot, calib, trans_mat, dist_coeffs,
        out, N, Pn, Wk - 1, wshift);
}